// Round 1
// baseline (9212.778 us; speedup 1.0000x reference)
//
#include <hip/hip_runtime.h>

// Problem constants (from reference)
#define NN   50000
#define EE   800000
#define INC  128
#define OUTC 256
#define HALF 128
#define NREL 6

// ---------------- GEMM: C[M,N] (ldc) = beta*C + (rowscale .* A[M,K]) @ B[K,N] (+bias, +relu)
#define BM 64
#define BN 64
#define BK 16

__global__ __launch_bounds__(256) void gemm_k(
    const float* __restrict__ A, int lda,
    const float* __restrict__ rowscale,   // per-row multiplier on A (nullptr = 1)
    const float* __restrict__ B, int ldb,
    float* __restrict__ C, int ldc,
    const float* __restrict__ bias,       // nullptr = none
    int M, int K, int N, int beta, int relu)
{
    __shared__ float As[BK][BM + 1];   // +1 pad: transposed store, stride 65 breaks conflicts
    __shared__ float Bs[BK][BN];
    const int tid = threadIdx.x;
    const int tx = tid & 15, ty = tid >> 4;
    const int bm = blockIdx.x * BM, bn = blockIdx.y * BN;
    const int row0 = ty * 4, col0 = tx * 4;

    float acc[4][4];
    if (beta) {
        #pragma unroll
        for (int i = 0; i < 4; ++i) {
            int gm = bm + row0 + i;
            #pragma unroll
            for (int j = 0; j < 4; ++j)
                acc[i][j] = (gm < M) ? C[(size_t)gm * ldc + bn + col0 + j] : 0.f;
        }
    } else {
        #pragma unroll
        for (int i = 0; i < 4; ++i)
            #pragma unroll
            for (int j = 0; j < 4; ++j)
                acc[i][j] = 0.f;
    }

    // staging index split: A: 16 k-lanes x 16 rows/sweep (4 sweeps); B: 64 n-lanes x 4 k/sweep
    const int la_k = tid & 15, la_m = tid >> 4;
    const int lb_n = tid & 63, lb_k = tid >> 6;

    // hoist row scales for the 4 A rows this thread stages
    float rsv[4];
    #pragma unroll
    for (int s = 0; s < 4; ++s) {
        int gm = bm + la_m + s * 16;
        rsv[s] = (rowscale && gm < M) ? rowscale[gm] : 1.0f;
    }

    for (int k0 = 0; k0 < K; k0 += BK) {
        #pragma unroll
        for (int s = 0; s < 4; ++s) {
            int m = la_m + s * 16;
            int gm = bm + m;
            float v = 0.f;
            if (gm < M) v = A[(size_t)gm * lda + k0 + la_k] * rsv[s];
            As[la_k][m] = v;
        }
        #pragma unroll
        for (int s = 0; s < 4; ++s) {
            int k = lb_k + s * 4;
            Bs[k][lb_n] = B[(size_t)(k0 + k) * ldb + bn + lb_n];
        }
        __syncthreads();
        #pragma unroll
        for (int kk = 0; kk < BK; ++kk) {
            float a[4], b[4];
            #pragma unroll
            for (int i = 0; i < 4; ++i) a[i] = As[kk][row0 + i];
            #pragma unroll
            for (int j = 0; j < 4; ++j) b[j] = Bs[kk][col0 + j];
            #pragma unroll
            for (int i = 0; i < 4; ++i)
                #pragma unroll
                for (int j = 0; j < 4; ++j)
                    acc[i][j] += a[i] * b[j];
        }
        __syncthreads();
    }

    #pragma unroll
    for (int i = 0; i < 4; ++i) {
        int gm = bm + row0 + i;
        if (gm < M) {
            #pragma unroll
            for (int j = 0; j < 4; ++j) {
                float v = acc[i][j];
                if (bias) v += bias[bn + col0 + j];
                if (relu) v = fmaxf(v, 0.f);
                C[(size_t)gm * ldc + bn + col0 + j] = v;
            }
        }
    }
}

// ---------------- edge-type counts (shared by all 3 layers)
__global__ __launch_bounds__(256) void count_k(const int* __restrict__ et,
                                               const int* __restrict__ dst,
                                               int* __restrict__ cnt)
{
    int e = blockIdx.x * 256 + threadIdx.x;
    if (e < EE) atomicAdd(&cnt[(size_t)et[e] * NN + dst[e]], 1);
}

__global__ __launch_bounds__(256) void inv_k(const int* __restrict__ cnt,
                                             float* __restrict__ inv, int n)
{
    int i = blockIdx.x * 256 + threadIdx.x;
    if (i < n) inv[i] = 1.0f / (float)max(cnt[i], 1);
}

// ---------------- scatter-add of source features into agg for one relation
// D4 = channels/4 (32 for d=128, 64 for d=256); 256/D4 edges per block.
template<int D4>
__global__ __launch_bounds__(256) void scatter_k(
    const float* __restrict__ X,           // [NN, 4*D4] row-major
    const int* __restrict__ src, const int* __restrict__ dst,
    const int* __restrict__ et, int rel,
    float* __restrict__ agg)               // [NN, 4*D4]
{
    constexpr int EPB = 256 / D4;
    const int c   = threadIdx.x % D4;
    const int sub = threadIdx.x / D4;
    const int e = blockIdx.x * EPB + sub;
    if (e >= EE) return;
    if (et[e] != rel) return;
    const int s = src[e], t = dst[e];
    const float4 v = ((const float4*)X)[(size_t)s * D4 + c];
    float* p = agg + ((size_t)t * D4 + c) * 4;
    unsafeAtomicAdd(p + 0, v.x);
    unsafeAtomicAdd(p + 1, v.y);
    unsafeAtomicAdd(p + 2, v.z);
    unsafeAtomicAdd(p + 3, v.w);
}

extern "C" void kernel_launch(void* const* d_in, const int* in_sizes, int n_in,
                              void* d_out, int out_size, void* d_ws, size_t ws_size,
                              hipStream_t stream)
{
    const float* x      = (const float*)d_in[0];
    const int*   ei     = (const int*)d_in[1];
    const int*   src    = ei;            // edge_index[0]
    const int*   dst    = ei + EE;       // edge_index[1]
    const int*   et     = (const int*)d_in[2];
    const float* enc_w0 = (const float*)d_in[3];
    const float* enc_b0 = (const float*)d_in[4];
    const float* enc_w1 = (const float*)d_in[5];
    const float* enc_b1 = (const float*)d_in[6];
    const float* enc_w2 = (const float*)d_in[7];
    const float* enc_b2 = (const float*)d_in[8];
    const float* W1     = (const float*)d_in[9];
    const float* root1  = (const float*)d_in[10];
    const float* b1     = (const float*)d_in[11];
    const float* W2     = (const float*)d_in[12];
    const float* root2  = (const float*)d_in[13];
    const float* b2     = (const float*)d_in[14];
    const float* W3     = (const float*)d_in[15];
    const float* root3  = (const float*)d_in[16];
    const float* b3     = (const float*)d_in[17];
    float* out = (float*)d_out;

    // workspace layout (floats): peak ~156 MB
    float* ws  = (float*)d_ws;
    float* B0  = ws;                         // 12.8M  h0 then g1
    float* B1  = ws + 12800000;              // 12.8M  h1 then g2
    float* AGG = ws + 25600000;              // 12.8M  per-relation agg (reused)
    int*   CNT = (int*)(ws + 38400000);      // 300k ints
    float* INV = ws + 38700000;              // 300k floats

    // ---- counts (shared by all layers; edge types fixed)
    hipMemsetAsync(CNT, 0, (size_t)NREL * NN * sizeof(int), stream);
    count_k<<<(EE + 255) / 256, 256, 0, stream>>>(et, dst, CNT);
    inv_k<<<(NREL * NN + 255) / 256, 256, 0, stream>>>(CNT, INV, NREL * NN);

    auto gemm = [&](const float* A, int lda, const float* rs,
                    const float* Bm, int ldb, float* C, int ldc,
                    const float* bias, int M, int K, int Ncols, int beta, int relu) {
        dim3 grid((M + BM - 1) / BM, Ncols / BN);
        gemm_k<<<grid, 256, 0, stream>>>(A, lda, rs, Bm, ldb, C, ldc, bias,
                                         M, K, Ncols, beta, relu);
    };

    // ---- dense encoder branch -> out[:, 0:128]
    gemm(x,  INC,  nullptr, enc_w0, OUTC, B0, OUTC, enc_b0, NN, INC,  OUTC, 0, 1);
    gemm(B0, OUTC, nullptr, enc_w1, OUTC, B1, OUTC, enc_b1, NN, OUTC, OUTC, 0, 1);
    gemm(B1, OUTC, nullptr, enc_w2, HALF, out, OUTC, enc_b2, NN, OUTC, HALF, 0, 0);

    // ---- conv1: x(128) -> g1 in B0
    gemm(x, INC, nullptr, root1, OUTC, B0, OUTC, b1, NN, INC, OUTC, 0, 0);
    for (int r = 0; r < NREL; ++r) {
        hipMemsetAsync(AGG, 0, (size_t)NN * INC * sizeof(float), stream);
        scatter_k<32><<<EE / 8, 256, 0, stream>>>(x, src, dst, et, r, AGG);
        gemm(AGG, INC, INV + (size_t)r * NN, W1 + (size_t)r * INC * OUTC, OUTC,
             B0, OUTC, nullptr, NN, INC, OUTC, 1, (r == NREL - 1) ? 1 : 0);
    }

    // ---- conv2: g1(256) -> g2 in B1
    gemm(B0, OUTC, nullptr, root2, OUTC, B1, OUTC, b2, NN, OUTC, OUTC, 0, 0);
    for (int r = 0; r < NREL; ++r) {
        hipMemsetAsync(AGG, 0, (size_t)NN * OUTC * sizeof(float), stream);
        scatter_k<64><<<EE / 4, 256, 0, stream>>>(B0, src, dst, et, r, AGG);
        gemm(AGG, OUTC, INV + (size_t)r * NN, W2 + (size_t)r * OUTC * OUTC, OUTC,
             B1, OUTC, nullptr, NN, OUTC, OUTC, 1, (r == NREL - 1) ? 1 : 0);
    }

    // ---- conv3: g2(256) -> out[:, 128:256]
    gemm(B1, OUTC, nullptr, root3, HALF, out + HALF, OUTC, b3, NN, OUTC, HALF, 0, 0);
    for (int r = 0; r < NREL; ++r) {
        hipMemsetAsync(AGG, 0, (size_t)NN * OUTC * sizeof(float), stream);
        scatter_k<64><<<EE / 4, 256, 0, stream>>>(B1, src, dst, et, r, AGG);
        gemm(AGG, OUTC, INV + (size_t)r * NN, W3 + (size_t)r * OUTC * HALF, HALF,
             out + HALF, OUTC, nullptr, NN, OUTC, HALF, 1, 0);
    }
}

// Round 2
// 963.500 us; speedup vs baseline: 9.5618x; 9.5618x over previous
//
#include <hip/hip_runtime.h>

#define NN   50000
#define EE   800000
#define INC  128
#define OUTC 256
#define HALF 128
#define NREL 6
#define NCELL (NN * NREL)   // 300000

typedef __attribute__((ext_vector_type(2))) short s16x2;
typedef __attribute__((ext_vector_type(4))) short s16x4;
typedef __attribute__((ext_vector_type(8))) short bf16x8;
typedef __attribute__((ext_vector_type(4))) float f32x4;

__device__ __forceinline__ float b2f(short b) {
    unsigned u = ((unsigned)(unsigned short)b) << 16;
    return __uint_as_float(u);
}
__device__ __forceinline__ short f2b(float f) {
    unsigned u = __float_as_uint(f);
    unsigned r = (u + 0x7fffu + ((u >> 16) & 1u)) >> 16;   // RNE
    return (short)r;
}

// ---------------- CSR build ----------------
__global__ __launch_bounds__(256) void count_k(const int* __restrict__ dst,
                                               const int* __restrict__ et,
                                               int* __restrict__ cnt) {
    int e = blockIdx.x * 256 + threadIdx.x;
    if (e < EE) atomicAdd(&cnt[dst[e] * NREL + et[e]], 1);
}

// block scans 512 cells (2/thread); writes block-local exclusive + block sum
__global__ __launch_bounds__(256) void scanA_k(const int* __restrict__ cnt,
                                               int* __restrict__ off,
                                               int* __restrict__ bsum, int n) {
    __shared__ int sh[256];
    int t = threadIdx.x;
    int base = blockIdx.x * 512 + t * 2;
    int v0 = (base < n) ? cnt[base] : 0;
    int v1 = (base + 1 < n) ? cnt[base + 1] : 0;
    int s = v0 + v1;
    sh[t] = s; __syncthreads();
    for (int o = 1; o < 256; o <<= 1) {
        int u = (t >= o) ? sh[t - o] : 0;
        __syncthreads();
        sh[t] += u;
        __syncthreads();
    }
    int excl = sh[t] - s;
    if (base < n)     off[base]     = excl;
    if (base + 1 < n) off[base + 1] = excl + v0;
    if (t == 255) bsum[blockIdx.x] = sh[255];
}

__global__ __launch_bounds__(1024) void scanB_k(int* __restrict__ bsum, int nb) {
    __shared__ int sh[1024];
    int t = threadIdx.x;
    int s = (t < nb) ? bsum[t] : 0;
    sh[t] = s; __syncthreads();
    for (int o = 1; o < 1024; o <<= 1) {
        int u = (t >= o) ? sh[t - o] : 0;
        __syncthreads();
        sh[t] += u;
        __syncthreads();
    }
    if (t < nb) bsum[t] = sh[t] - s;   // exclusive, in place
}

__global__ __launch_bounds__(256) void scanC_k(int* __restrict__ off,
                                               const int* __restrict__ bsum, int n) {
    int i = blockIdx.x * 256 + threadIdx.x;
    if (i < n) off[i] += bsum[i >> 9];
    if (i == 0) off[n] = EE;
}

__global__ __launch_bounds__(256) void copyint_k(const int* __restrict__ a,
                                                 int* __restrict__ b, int n) {
    int i = blockIdx.x * 256 + threadIdx.x;
    if (i < n) b[i] = a[i];
}

__global__ __launch_bounds__(256) void fill_k(const int* __restrict__ src,
                                              const int* __restrict__ dst,
                                              const int* __restrict__ et,
                                              int* __restrict__ cur,
                                              int* __restrict__ es) {
    int e = blockIdx.x * 256 + threadIdx.x;
    if (e < EE) {
        int key = dst[e] * NREL + et[e];
        int p = atomicAdd(&cur[key], 1);
        es[p] = src[e];
    }
}

// ---------------- casts / copies ----------------
__global__ __launch_bounds__(256) void cast_x_k(const float* __restrict__ x,
                                                short* __restrict__ xb, int n4) {
    int i = blockIdx.x * 256 + threadIdx.x;
    if (i < n4) {
        float4 v = ((const float4*)x)[i];
        s16x4 o;
        o[0] = f2b(v.x); o[1] = f2b(v.y); o[2] = f2b(v.z); o[3] = f2b(v.w);
        ((s16x4*)xb)[i] = o;
    }
}

// WT[Ncols][Ktot] = [root; W]^T  (bf16)
__global__ __launch_bounds__(256) void wtcat_k(const float* __restrict__ root,
                                               const float* __restrict__ W,
                                               int K0, int Ktot, int Ncols,
                                               short* __restrict__ WT) {
    int i = blockIdx.x * 256 + threadIdx.x;
    if (i >= Ncols * Ktot) return;
    int n = i / Ktot, k = i - n * Ktot;
    float v = (k < K0) ? root[(size_t)k * Ncols + n]
                       : W[(size_t)(k - K0) * Ncols + n];
    WT[(size_t)n * Ktot + k] = f2b(v);
}

// copy nrows x D bf16 rows: src rows node0.. (ld ls) -> dst rows 0.. (ld ld)
__global__ __launch_bounds__(256) void copyrows_k(const short* __restrict__ src, int ls,
                                                  short* __restrict__ dst, int ld,
                                                  int node0, int nrows, int D) {
    int g8 = D >> 3;
    int i = blockIdx.x * 256 + threadIdx.x;
    if (i >= nrows * g8) return;
    int row = i / g8, g = i - row * g8;
    *(uint4*)&dst[(size_t)row * ld + g * 8] =
        *(const uint4*)&src[(size_t)(node0 + row) * ls + g * 8];
}

// ---------------- per-(node,rel) mean gather ----------------
// one wave per cell; writes mean row (zeros if no edges) into ACAT rel-block
template<int D>
__global__ __launch_bounds__(256) void agg_k(const short* __restrict__ X, int ldx,
                                             const int* __restrict__ off,
                                             const int* __restrict__ es,
                                             short* __restrict__ AC, int lda,
                                             int node0, int ncells) {
    constexpr int CPL = D / 64;                // channels per lane (2 or 4)
    int ci = blockIdx.x * 4 + (threadIdx.x >> 6);
    if (ci >= ncells) return;
    int lane = threadIdx.x & 63;
    int node = ci / NREL, rel = ci - node * NREL;
    int gcell = (node0 + node) * NREL + rel;
    int beg = off[gcell], end = off[gcell + 1];
    int c0 = lane * CPL;
    float s[CPL];
    #pragma unroll
    for (int i = 0; i < CPL; ++i) s[i] = 0.f;
    for (int j = beg; j < end; ++j) {
        const short* p = X + (size_t)es[j] * ldx + c0;
        if constexpr (CPL == 4) {
            s16x4 v = *(const s16x4*)p;
            #pragma unroll
            for (int i = 0; i < 4; ++i) s[i] += b2f(v[i]);
        } else {
            s16x2 v = *(const s16x2*)p;
            #pragma unroll
            for (int i = 0; i < 2; ++i) s[i] += b2f(v[i]);
        }
    }
    float inv = (end > beg) ? 1.f / (float)(end - beg) : 0.f;
    short* q = AC + (size_t)node * lda + D + rel * D + c0;
    if constexpr (CPL == 4) {
        s16x4 o;
        #pragma unroll
        for (int i = 0; i < 4; ++i) o[i] = f2b(s[i] * inv);
        *(s16x4*)q = o;
    } else {
        s16x2 o;
        #pragma unroll
        for (int i = 0; i < 2; ++i) o[i] = f2b(s[i] * inv);
        *(s16x2*)q = o;
    }
}

// ---------------- bf16 MFMA GEMM: C = A[M,K] @ BT[N,K]^T (+bias,+relu) ----------------
// A row-major bf16 (rows padded to grid), BT row-major bf16 [Ncols][K].
// Writes bf16 (Cb,ldcb) or fp32 (Cf,ldcf); store guarded by grow < M.
#define LDSP 40   // padded LDS row stride (shorts) — breaks 8-way frag-read conflicts

__global__ __launch_bounds__(256) void gemm_bt_k(
    const short* __restrict__ A, int lda,
    const short* __restrict__ BT,
    int M, int K, int Ncols,
    const float* __restrict__ bias, int relu,
    short* __restrict__ Cb, int ldcb,
    float* __restrict__ Cf, int ldcf) {
    __shared__ __align__(16) short As[128 * LDSP];
    __shared__ __align__(16) short Bs[128 * LDSP];
    const int tid = threadIdx.x;
    const int wave = tid >> 6, lane = tid & 63;
    const int wm = (wave & 1) * 64, wn = (wave >> 1) * 64;
    const int l16 = lane & 15, quad = lane >> 4;
    const int bm = blockIdx.x * 128, bn = blockIdx.y * 128;

    f32x4 acc[4][4];
    #pragma unroll
    for (int i = 0; i < 4; ++i)
        #pragma unroll
        for (int j = 0; j < 4; ++j)
            acc[i][j] = (f32x4)0.f;

    for (int k0 = 0; k0 < K; k0 += 32) {
        #pragma unroll
        for (int s = 0; s < 2; ++s) {
            int g = tid * 2 + s;              // 512 groups of 8 shorts
            int row = g >> 2, c16 = g & 3;
            *(uint4*)&As[row * LDSP + c16 * 8] =
                *(const uint4*)&A[(size_t)(bm + row) * lda + k0 + c16 * 8];
            *(uint4*)&Bs[row * LDSP + c16 * 8] =
                *(const uint4*)&BT[(size_t)(bn + row) * K + k0 + c16 * 8];
        }
        __syncthreads();
        bf16x8 af[4], bf[4];
        #pragma unroll
        for (int mt = 0; mt < 4; ++mt)
            af[mt] = *(const bf16x8*)&As[(wm + mt * 16 + l16) * LDSP + quad * 8];
        #pragma unroll
        for (int nt = 0; nt < 4; ++nt)
            bf[nt] = *(const bf16x8*)&Bs[(wn + nt * 16 + l16) * LDSP + quad * 8];
        #pragma unroll
        for (int mt = 0; mt < 4; ++mt)
            #pragma unroll
            for (int nt = 0; nt < 4; ++nt)
                acc[mt][nt] = __builtin_amdgcn_mfma_f32_16x16x32_bf16(
                    af[mt], bf[nt], acc[mt][nt], 0, 0, 0);
        __syncthreads();
    }

    float bv[4];
    #pragma unroll
    for (int nt = 0; nt < 4; ++nt) bv[nt] = bias[bn + wn + nt * 16 + l16];

    #pragma unroll
    for (int mt = 0; mt < 4; ++mt) {
        int r0 = bm + wm + mt * 16 + quad * 4;
        #pragma unroll
        for (int nt = 0; nt < 4; ++nt) {
            int gc = bn + wn + nt * 16 + l16;
            #pragma unroll
            for (int r = 0; r < 4; ++r) {
                int grow = r0 + r;
                if (grow < M) {
                    float v = acc[mt][nt][r] + bv[nt];
                    if (relu) v = fmaxf(v, 0.f);
                    if (Cb) Cb[(size_t)grow * ldcb + gc] = f2b(v);
                    else    Cf[(size_t)grow * ldcf + gc] = v;
                }
            }
        }
    }
}

// ---------------- host ----------------
extern "C" void kernel_launch(void* const* d_in, const int* in_sizes, int n_in,
                              void* d_out, int out_size, void* d_ws, size_t ws_size,
                              hipStream_t stream) {
    const float* x      = (const float*)d_in[0];
    const int*   ei     = (const int*)d_in[1];
    const int*   srcv   = ei;
    const int*   dstv   = ei + EE;
    const int*   et     = (const int*)d_in[2];
    const float* enc_w0 = (const float*)d_in[3];
    const float* enc_b0 = (const float*)d_in[4];
    const float* enc_w1 = (const float*)d_in[5];
    const float* enc_b1 = (const float*)d_in[6];
    const float* enc_w2 = (const float*)d_in[7];
    const float* enc_b2 = (const float*)d_in[8];
    const float* W1     = (const float*)d_in[9];
    const float* root1  = (const float*)d_in[10];
    const float* b1     = (const float*)d_in[11];
    const float* W2     = (const float*)d_in[12];
    const float* root2  = (const float*)d_in[13];
    const float* b2     = (const float*)d_in[14];
    const float* W3     = (const float*)d_in[15];
    const float* root3  = (const float*)d_in[16];
    const float* b3     = (const float*)d_in[17];
    float* out = (float*)d_out;

    const int NPAD = 50048;                    // 391*128

    // workspace carve-up
    char* p = (char*)d_ws;
    auto alloc = [&](size_t bytes) -> char* {
        char* r = p; p += (bytes + 255) & ~(size_t)255; return r;
    };
    short* xb  = (short*)alloc((size_t)NPAD * INC * 2);
    short* g1  = (short*)alloc((size_t)NPAD * OUTC * 2);
    short* g2  = (short*)alloc((size_t)NPAD * OUTC * 2);
    short* WT1 = (short*)alloc((size_t)OUTC * 896 * 2);
    short* WT2 = (short*)alloc((size_t)OUTC * 1792 * 2);
    short* WT3 = (short*)alloc((size_t)HALF * 1792 * 2);
    short* ET0 = (short*)alloc((size_t)OUTC * INC * 2);
    short* ET1 = (short*)alloc((size_t)OUTC * OUTC * 2);
    short* ET2 = (short*)alloc((size_t)HALF * OUTC * 2);
    int* CNT  = (int*)alloc((size_t)NCELL * 4);
    int* OFF  = (int*)alloc((size_t)(NCELL + 1) * 4);
    int* CUR  = (int*)alloc((size_t)NCELL * 4);
    int* ES   = (int*)alloc((size_t)EE * 4);
    int* BSUM = (int*)alloc(1024 * 4);
    size_t fixed = (size_t)(p - (char*)d_ws);

    int chunk = 25000;
    if (fixed + (size_t)25088 * 1792 * 2 > ws_size) chunk = 12500;
    if (fixed + (size_t)12544 * 1792 * 2 > ws_size && chunk == 12500) chunk = 6250;
    int crpad = ((chunk + 127) / 128) * 128;
    short* ACAT = (short*)alloc((size_t)crpad * 1792 * 2);

    // ---- CSR build (once; reused by all 3 layers)
    hipMemsetAsync(CNT, 0, (size_t)NCELL * 4, stream);
    count_k<<<EE / 256, 256, 0, stream>>>(dstv, et, CNT);
    int nbA = (NCELL + 511) / 512;             // 586
    scanA_k<<<nbA, 256, 0, stream>>>(CNT, OFF, BSUM, NCELL);
    scanB_k<<<1, 1024, 0, stream>>>(BSUM, nbA);
    scanC_k<<<(NCELL + 255) / 256, 256, 0, stream>>>(OFF, BSUM, NCELL);
    copyint_k<<<(NCELL + 255) / 256, 256, 0, stream>>>(OFF, CUR, NCELL);
    fill_k<<<EE / 256, 256, 0, stream>>>(srcv, dstv, et, CUR, ES);

    // ---- weight transposes + input cast
    cast_x_k<<<(NN * INC / 4 + 255) / 256, 256, 0, stream>>>(x, xb, NN * INC / 4);
    wtcat_k<<<(OUTC * 896 + 255) / 256, 256, 0, stream>>>(root1, W1, INC, 896, OUTC, WT1);
    wtcat_k<<<(OUTC * 1792 + 255) / 256, 256, 0, stream>>>(root2, W2, OUTC, 1792, OUTC, WT2);
    wtcat_k<<<(HALF * 1792 + 255) / 256, 256, 0, stream>>>(root3, W3, OUTC, 1792, HALF, WT3);
    wtcat_k<<<(OUTC * INC + 255) / 256, 256, 0, stream>>>(enc_w0, nullptr, INC, INC, OUTC, ET0);
    wtcat_k<<<(OUTC * OUTC + 255) / 256, 256, 0, stream>>>(enc_w1, nullptr, OUTC, OUTC, OUTC, ET1);
    wtcat_k<<<(HALF * OUTC + 255) / 256, 256, 0, stream>>>(enc_w2, nullptr, OUTC, OUTC, HALF, ET2);

    auto gemm = [&](const short* A, int lda, const short* BT, int M, int K, int Ncols,
                    const float* bias, int relu, short* Cb, int ldcb, float* Cf, int ldcf) {
        dim3 grid((M + 127) / 128, Ncols / 128);
        gemm_bt_k<<<grid, 256, 0, stream>>>(A, lda, BT, M, K, Ncols, bias, relu,
                                            Cb, ldcb, Cf, ldcf);
    };

    // ---- encoder (uses g1/g2 as ping-pong before convs need them)
    gemm(xb, INC, ET0, NN, INC, OUTC, enc_b0, 1, g1, OUTC, nullptr, 0);
    gemm(g1, OUTC, ET1, NN, OUTC, OUTC, enc_b1, 1, g2, OUTC, nullptr, 0);
    gemm(g2, OUTC, ET2, NN, OUTC, HALF, enc_b2, 0, nullptr, 0, out, OUTC);

    // ---- conv1: xb(128) -> g1
    for (int c0 = 0; c0 < NN; c0 += chunk) {
        int nc = chunk * NREL;
        copyrows_k<<<(chunk * (INC / 8) + 255) / 256, 256, 0, stream>>>(
            xb, INC, ACAT, 896, c0, chunk, INC);
        agg_k<INC><<<(nc + 3) / 4, 256, 0, stream>>>(xb, INC, OFF, ES, ACAT, 896, c0, nc);
        gemm(ACAT, 896, WT1, chunk, 896, OUTC, b1, 1, g1 + (size_t)c0 * OUTC, OUTC, nullptr, 0);
    }
    // ---- conv2: g1(256) -> g2
    for (int c0 = 0; c0 < NN; c0 += chunk) {
        int nc = chunk * NREL;
        copyrows_k<<<(chunk * (OUTC / 8) + 255) / 256, 256, 0, stream>>>(
            g1, OUTC, ACAT, 1792, c0, chunk, OUTC);
        agg_k<OUTC><<<(nc + 3) / 4, 256, 0, stream>>>(g1, OUTC, OFF, ES, ACAT, 1792, c0, nc);
        gemm(ACAT, 1792, WT2, chunk, 1792, OUTC, b2, 1, g2 + (size_t)c0 * OUTC, OUTC, nullptr, 0);
    }
    // ---- conv3: g2(256) -> out[:,128:]
    for (int c0 = 0; c0 < NN; c0 += chunk) {
        int nc = chunk * NREL;
        copyrows_k<<<(chunk * (OUTC / 8) + 255) / 256, 256, 0, stream>>>(
            g2, OUTC, ACAT, 1792, c0, chunk, OUTC);
        agg_k<OUTC><<<(nc + 3) / 4, 256, 0, stream>>>(g2, OUTC, OFF, ES, ACAT, 1792, c0, nc);
        gemm(ACAT, 1792, WT3, chunk, 1792, HALF, b3, 0, nullptr, 0,
             out + (size_t)c0 * OUTC + HALF, OUTC);
    }
}

// Round 3
// 752.667 us; speedup vs baseline: 12.2402x; 1.2801x over previous
//
#include <hip/hip_runtime.h>

#define NN   50000
#define EE   800000
#define INC  128
#define OUTC 256
#define HALF 128
#define NREL 6
#define NCELL (NN * NREL)   // 300000

typedef __attribute__((ext_vector_type(4))) short s16x4;
typedef __attribute__((ext_vector_type(8))) short bf16x8;
typedef __attribute__((ext_vector_type(4))) float f32x4;

__device__ __forceinline__ float b2f(short b) {
    unsigned u = ((unsigned)(unsigned short)b) << 16;
    return __uint_as_float(u);
}
__device__ __forceinline__ short f2b(float f) {
    unsigned u = __float_as_uint(f);
    unsigned r = (u + 0x7fffu + ((u >> 16) & 1u)) >> 16;   // RNE
    return (short)r;
}

__device__ __forceinline__ void gload16(const void* g, void* l) {
    __builtin_amdgcn_global_load_lds(
        (const __attribute__((address_space(1))) void*)g,
        (__attribute__((address_space(3))) void*)l, 16, 0, 0);
}

// ---------------- CSR build ----------------
__global__ __launch_bounds__(256) void count_k(const int* __restrict__ dst,
                                               const int* __restrict__ et,
                                               int* __restrict__ cnt) {
    int e = blockIdx.x * 256 + threadIdx.x;
    if (e < EE) atomicAdd(&cnt[dst[e] * NREL + et[e]], 1);
}

__global__ __launch_bounds__(256) void scanA_k(const int* __restrict__ cnt,
                                               int* __restrict__ off,
                                               int* __restrict__ bsum, int n) {
    __shared__ int sh[256];
    int t = threadIdx.x;
    int base = blockIdx.x * 512 + t * 2;
    int v0 = (base < n) ? cnt[base] : 0;
    int v1 = (base + 1 < n) ? cnt[base + 1] : 0;
    int s = v0 + v1;
    sh[t] = s; __syncthreads();
    for (int o = 1; o < 256; o <<= 1) {
        int u = (t >= o) ? sh[t - o] : 0;
        __syncthreads();
        sh[t] += u;
        __syncthreads();
    }
    int excl = sh[t] - s;
    if (base < n)     off[base]     = excl;
    if (base + 1 < n) off[base + 1] = excl + v0;
    if (t == 255) bsum[blockIdx.x] = sh[255];
}

__global__ __launch_bounds__(1024) void scanB_k(int* __restrict__ bsum, int nb) {
    __shared__ int sh[1024];
    int t = threadIdx.x;
    int s = (t < nb) ? bsum[t] : 0;
    sh[t] = s; __syncthreads();
    for (int o = 1; o < 1024; o <<= 1) {
        int u = (t >= o) ? sh[t - o] : 0;
        __syncthreads();
        sh[t] += u;
        __syncthreads();
    }
    if (t < nb) bsum[t] = sh[t] - s;
}

__global__ __launch_bounds__(256) void scanC_k(int* __restrict__ off,
                                               const int* __restrict__ bsum, int n) {
    int i = blockIdx.x * 256 + threadIdx.x;
    if (i < n) off[i] += bsum[i >> 9];
    if (i == 0) off[n] = EE;
}

__global__ __launch_bounds__(256) void copyint_k(const int* __restrict__ a,
                                                 int* __restrict__ b, int n) {
    int i = blockIdx.x * 256 + threadIdx.x;
    if (i < n) b[i] = a[i];
}

__global__ __launch_bounds__(256) void fill_k(const int* __restrict__ src,
                                              const int* __restrict__ dst,
                                              const int* __restrict__ et,
                                              int* __restrict__ cur,
                                              int* __restrict__ es) {
    int e = blockIdx.x * 256 + threadIdx.x;
    if (e < EE) {
        int key = dst[e] * NREL + et[e];
        int p = atomicAdd(&cur[key], 1);
        es[p] = src[e];
    }
}

// ---------------- casts ----------------
__global__ __launch_bounds__(256) void cast_x_k(const float* __restrict__ x,
                                                short* __restrict__ xb, int n4) {
    int i = blockIdx.x * 256 + threadIdx.x;
    if (i < n4) {
        float4 v = ((const float4*)x)[i];
        s16x4 o;
        o[0] = f2b(v.x); o[1] = f2b(v.y); o[2] = f2b(v.z); o[3] = f2b(v.w);
        ((s16x4*)xb)[i] = o;
    }
}

// WT[Ncols][Ktot] = [root; W]^T  (bf16)
__global__ __launch_bounds__(256) void wtcat_k(const float* __restrict__ root,
                                               const float* __restrict__ W,
                                               int K0, int Ktot, int Ncols,
                                               short* __restrict__ WT) {
    int i = blockIdx.x * 256 + threadIdx.x;
    if (i >= Ncols * Ktot) return;
    int n = i / Ktot, k = i - n * Ktot;
    float v = (k < K0) ? root[(size_t)k * Ncols + n]
                       : W[(size_t)(k - K0) * Ncols + n];
    WT[(size_t)n * Ktot + k] = f2b(v);
}

// ---------------- per-(node,rel) mean gather into AG [node][rel*D + c] ----------------
template<int D>
__global__ __launch_bounds__(256) void agg_k(const short* __restrict__ X, int ldx,
                                             const int* __restrict__ off,
                                             const int* __restrict__ es,
                                             short* __restrict__ AG, int lda,
                                             int node0, int ncells) {
    constexpr int LPC = D / 4;                 // lanes per cell (32 or 64)
    int sub  = threadIdx.x / LPC;
    int lane = threadIdx.x % LPC;
    int ci = blockIdx.x * (256 / LPC) + sub;
    if (ci >= ncells) return;
    int node = ci / NREL, rel = ci - node * NREL;
    int gcell = (node0 + node) * NREL + rel;
    int beg = off[gcell], end = off[gcell + 1];
    int c0 = lane * 4;
    float s0 = 0.f, s1 = 0.f, s2 = 0.f, s3 = 0.f;
    int j = beg;
    for (; j + 1 < end; j += 2) {
        s16x4 v = *(const s16x4*)(X + (size_t)es[j] * ldx + c0);
        s16x4 w = *(const s16x4*)(X + (size_t)es[j + 1] * ldx + c0);
        s0 += b2f(v[0]) + b2f(w[0]);
        s1 += b2f(v[1]) + b2f(w[1]);
        s2 += b2f(v[2]) + b2f(w[2]);
        s3 += b2f(v[3]) + b2f(w[3]);
    }
    if (j < end) {
        s16x4 v = *(const s16x4*)(X + (size_t)es[j] * ldx + c0);
        s0 += b2f(v[0]); s1 += b2f(v[1]); s2 += b2f(v[2]); s3 += b2f(v[3]);
    }
    float inv = (end > beg) ? 1.f / (float)(end - beg) : 0.f;
    s16x4 o;
    o[0] = f2b(s0 * inv); o[1] = f2b(s1 * inv);
    o[2] = f2b(s2 * inv); o[3] = f2b(s3 * inv);
    *(s16x4*)(AG + (size_t)node * lda + rel * D + c0) = o;
}

// ---------------- bf16 MFMA GEMM with split A (self | agg) ----------------
// C[M,Ncols] = [A0 | A1] @ BT^T  (+bias, +relu).  k < Ksplit from A0, else A1.
// LDS tiles 128x32 bf16, stored as 16B chunks with XOR swizzle:
//   chunk (r, c) at slot r*4 + (c ^ (r&3))  -> uniform 8/bank for b128 frag reads,
//   and slot index == DMA lane order (global_load_lds needs contiguous lane dest).
#define ACH(R, q) (((((R) << 2) | ((q) ^ ((R) & 3)))) * 8)

__global__ __launch_bounds__(256) void gemm_bt_k(
    const short* __restrict__ A0, int ld0,
    const short* __restrict__ A1, int ld1, int Ksplit,
    const short* __restrict__ BT,
    int M, int K, int Ncols,
    const float* __restrict__ bias, int relu,
    short* __restrict__ Cb, int ldcb,
    float* __restrict__ Cf, int ldcf) {
    __shared__ __align__(16) short As[128 * 32];
    __shared__ __align__(16) short Bs[128 * 32];
    const int tid = threadIdx.x;
    const int wave = tid >> 6, lane = tid & 63;
    const int wm = (wave & 1) * 64, wn = (wave >> 1) * 64;
    const int l16 = lane & 15, quad = lane >> 4;
    const int bm = blockIdx.x * 128, bn = blockIdx.y * 128;

    // staging slots: s0 = tid (0..255), s1 = tid + 256
    const int s0 = tid, s1 = tid + 256;
    const int r0 = s0 >> 2, c0 = (s0 & 3) ^ (r0 & 3);
    const int r1 = s1 >> 2, c1 = (s1 & 3) ^ (r1 & 3);
    short* lA0 = &As[(size_t)(wave * 64) * 8];
    short* lA1 = &As[(size_t)(256 + wave * 64) * 8];
    short* lB0 = &Bs[(size_t)(wave * 64) * 8];
    short* lB1 = &Bs[(size_t)(256 + wave * 64) * 8];

    f32x4 acc[4][4];
    #pragma unroll
    for (int i = 0; i < 4; ++i)
        #pragma unroll
        for (int j = 0; j < 4; ++j)
            acc[i][j] = (f32x4)0.f;

    for (int k0 = 0; k0 < K; k0 += 32) {
        const short* Ab; int lda; int kk;
        if (k0 < Ksplit) { Ab = A0; lda = ld0; kk = k0; }
        else             { Ab = A1; lda = ld1; kk = k0 - Ksplit; }
        gload16(Ab + (size_t)(bm + r0) * lda + kk + c0 * 8, lA0);
        gload16(Ab + (size_t)(bm + r1) * lda + kk + c1 * 8, lA1);
        gload16(BT + (size_t)(bn + r0) * K + k0 + c0 * 8, lB0);
        gload16(BT + (size_t)(bn + r1) * K + k0 + c1 * 8, lB1);
        __syncthreads();
        bf16x8 af[4], bf[4];
        #pragma unroll
        for (int mt = 0; mt < 4; ++mt)
            af[mt] = *(const bf16x8*)&As[ACH(wm + mt * 16 + l16, quad)];
        #pragma unroll
        for (int nt = 0; nt < 4; ++nt)
            bf[nt] = *(const bf16x8*)&Bs[ACH(wn + nt * 16 + l16, quad)];
        #pragma unroll
        for (int mt = 0; mt < 4; ++mt)
            #pragma unroll
            for (int nt = 0; nt < 4; ++nt)
                acc[mt][nt] = __builtin_amdgcn_mfma_f32_16x16x32_bf16(
                    af[mt], bf[nt], acc[mt][nt], 0, 0, 0);
        __syncthreads();
    }

    float bv[4];
    #pragma unroll
    for (int nt = 0; nt < 4; ++nt) bv[nt] = bias[bn + wn + nt * 16 + l16];

    #pragma unroll
    for (int mt = 0; mt < 4; ++mt) {
        int rb = bm + wm + mt * 16 + quad * 4;
        #pragma unroll
        for (int nt = 0; nt < 4; ++nt) {
            int gc = bn + wn + nt * 16 + l16;
            #pragma unroll
            for (int r = 0; r < 4; ++r) {
                int grow = rb + r;
                if (grow < M) {
                    float v = acc[mt][nt][r] + bv[nt];
                    if (relu) v = fmaxf(v, 0.f);
                    if (Cb) Cb[(size_t)grow * ldcb + gc] = f2b(v);
                    else    Cf[(size_t)grow * ldcf + gc] = v;
                }
            }
        }
    }
}

// ---------------- host ----------------
extern "C" void kernel_launch(void* const* d_in, const int* in_sizes, int n_in,
                              void* d_out, int out_size, void* d_ws, size_t ws_size,
                              hipStream_t stream) {
    const float* x      = (const float*)d_in[0];
    const int*   ei     = (const int*)d_in[1];
    const int*   srcv   = ei;
    const int*   dstv   = ei + EE;
    const int*   et     = (const int*)d_in[2];
    const float* enc_w0 = (const float*)d_in[3];
    const float* enc_b0 = (const float*)d_in[4];
    const float* enc_w1 = (const float*)d_in[5];
    const float* enc_b1 = (const float*)d_in[6];
    const float* enc_w2 = (const float*)d_in[7];
    const float* enc_b2 = (const float*)d_in[8];
    const float* W1     = (const float*)d_in[9];
    const float* root1  = (const float*)d_in[10];
    const float* b1     = (const float*)d_in[11];
    const float* W2     = (const float*)d_in[12];
    const float* root2  = (const float*)d_in[13];
    const float* b2     = (const float*)d_in[14];
    const float* W3     = (const float*)d_in[15];
    const float* root3  = (const float*)d_in[16];
    const float* b3     = (const float*)d_in[17];
    float* out = (float*)d_out;

    const int NPAD = 50048;                    // 391*128

    char* p = (char*)d_ws;
    auto alloc = [&](size_t bytes) -> char* {
        char* r = p; p += (bytes + 255) & ~(size_t)255; return r;
    };
    short* xb  = (short*)alloc((size_t)NPAD * INC * 2);
    short* g1  = (short*)alloc((size_t)NPAD * OUTC * 2);
    short* g2  = (short*)alloc((size_t)NPAD * OUTC * 2);
    short* WT1 = (short*)alloc((size_t)OUTC * 896 * 2);
    short* WT2 = (short*)alloc((size_t)OUTC * 1792 * 2);
    short* WT3 = (short*)alloc((size_t)HALF * 1792 * 2);
    short* ET0 = (short*)alloc((size_t)OUTC * INC * 2);
    short* ET1 = (short*)alloc((size_t)OUTC * OUTC * 2);
    short* ET2 = (short*)alloc((size_t)HALF * OUTC * 2);
    int* CNT  = (int*)alloc((size_t)NCELL * 4);
    int* OFF  = (int*)alloc((size_t)(NCELL + 1) * 4);
    int* CUR  = (int*)alloc((size_t)NCELL * 4);
    int* ES   = (int*)alloc((size_t)EE * 4);
    int* BSUM = (int*)alloc(1024 * 4);
    size_t fixed = (size_t)(p - (char*)d_ws);

    // agg buffer holds only the 6 relation blocks (self comes straight from A0)
    int chunk = 50000;
    if (fixed + (size_t)50048 * 1536 * 2 > ws_size) chunk = 25000;
    if (chunk == 25000 && fixed + (size_t)25088 * 1536 * 2 > ws_size) chunk = 12500;
    int crpad = ((chunk + 127) / 128) * 128;
    short* AG = (short*)alloc((size_t)crpad * 1536 * 2);

    // ---- CSR build (once; edge structure shared by all 3 layers)
    hipMemsetAsync(CNT, 0, (size_t)NCELL * 4, stream);
    count_k<<<EE / 256, 256, 0, stream>>>(dstv, et, CNT);
    int nbA = (NCELL + 511) / 512;
    scanA_k<<<nbA, 256, 0, stream>>>(CNT, OFF, BSUM, NCELL);
    scanB_k<<<1, 1024, 0, stream>>>(BSUM, nbA);
    scanC_k<<<(NCELL + 255) / 256, 256, 0, stream>>>(OFF, BSUM, NCELL);
    copyint_k<<<(NCELL + 255) / 256, 256, 0, stream>>>(OFF, CUR, NCELL);
    fill_k<<<EE / 256, 256, 0, stream>>>(srcv, dstv, et, CUR, ES);

    // ---- weight transposes + input cast
    cast_x_k<<<(NN * INC / 4 + 255) / 256, 256, 0, stream>>>(x, xb, NN * INC / 4);
    wtcat_k<<<(OUTC * 896 + 255) / 256, 256, 0, stream>>>(root1, W1, INC, 896, OUTC, WT1);
    wtcat_k<<<(OUTC * 1792 + 255) / 256, 256, 0, stream>>>(root2, W2, OUTC, 1792, OUTC, WT2);
    wtcat_k<<<(HALF * 1792 + 255) / 256, 256, 0, stream>>>(root3, W3, OUTC, 1792, HALF, WT3);
    wtcat_k<<<(OUTC * INC + 255) / 256, 256, 0, stream>>>(enc_w0, nullptr, INC, INC, OUTC, ET0);
    wtcat_k<<<(OUTC * OUTC + 255) / 256, 256, 0, stream>>>(enc_w1, nullptr, OUTC, OUTC, OUTC, ET1);
    wtcat_k<<<(HALF * OUTC + 255) / 256, 256, 0, stream>>>(enc_w2, nullptr, OUTC, OUTC, HALF, ET2);

    auto gemm = [&](const short* A0, int ld0, const short* A1, int ld1, int Ksplit,
                    const short* BT, int M, int K, int Ncols,
                    const float* bias, int relu, short* Cb, int ldcb, float* Cf, int ldcf) {
        dim3 grid((M + 127) / 128, Ncols / 128);
        gemm_bt_k<<<grid, 256, 0, stream>>>(A0, ld0, A1, ld1, Ksplit, BT,
                                            M, K, Ncols, bias, relu, Cb, ldcb, Cf, ldcf);
    };

    // ---- encoder
    gemm(xb, INC, nullptr, 0, INC, ET0, NN, INC, OUTC, enc_b0, 1, g1, OUTC, nullptr, 0);
    gemm(g1, OUTC, nullptr, 0, OUTC, ET1, NN, OUTC, OUTC, enc_b1, 1, g2, OUTC, nullptr, 0);
    gemm(g2, OUTC, nullptr, 0, OUTC, ET2, NN, OUTC, HALF, enc_b2, 0, nullptr, 0, out, OUTC);

    // ---- conv1: xb(128) -> g1
    for (int c0 = 0; c0 < NN; c0 += chunk) {
        int nc = chunk * NREL;
        agg_k<INC><<<(nc + 7) / 8, 256, 0, stream>>>(xb, INC, OFF, ES, AG, 768, c0, nc);
        gemm(xb + (size_t)c0 * INC, INC, AG, 768, INC, WT1, chunk, 896, OUTC,
             b1, 1, g1 + (size_t)c0 * OUTC, OUTC, nullptr, 0);
    }
    // ---- conv2: g1(256) -> g2
    for (int c0 = 0; c0 < NN; c0 += chunk) {
        int nc = chunk * NREL;
        agg_k<OUTC><<<(nc + 3) / 4, 256, 0, stream>>>(g1, OUTC, OFF, ES, AG, 1536, c0, nc);
        gemm(g1 + (size_t)c0 * OUTC, OUTC, AG, 1536, OUTC, WT2, chunk, 1792, OUTC,
             b2, 1, g2 + (size_t)c0 * OUTC, OUTC, nullptr, 0);
    }
    // ---- conv3: g2(256) -> out[:,128:]
    for (int c0 = 0; c0 < NN; c0 += chunk) {
        int nc = chunk * NREL;
        agg_k<OUTC><<<(nc + 3) / 4, 256, 0, stream>>>(g2, OUTC, OFF, ES, AG, 1536, c0, nc);
        gemm(g2 + (size_t)c0 * OUTC, OUTC, AG, 1536, OUTC, WT3, chunk, 1792, HALF,
             b3, 0, nullptr, 0, out + (size_t)c0 * OUTC + HALF, OUTC);
    }
}